// Round 1
// baseline (3671.172 us; speedup 1.0000x reference)
//
#include <hip/hip_runtime.h>

#define B_ 16
#define F_ 32
#define C_ 32
#define T_ 2048
#define K_ 129
#define TT 256
#define WIN 384      // z window per channel row: TT + 128 (tau in [t0-64, t0+319])
#define NCH 64       // 2*F
#define WROW 128     // staged weight taps j in [0,128); j=128 handled in epilogue
#define NTHREADS 512

__device__ __forceinline__ unsigned short f2bf(float f) {
    unsigned int u = __float_as_uint(f);
    unsigned int r = u + 0x7fffu + ((u >> 16) & 1u);   // round-to-nearest-even
    return (unsigned short)(r >> 16);
}

__device__ __forceinline__ void cvt8(const uint4 v, float* f) {
    f[0] = __uint_as_float(v.x << 16); f[1] = __uint_as_float(v.x & 0xffff0000u);
    f[2] = __uint_as_float(v.y << 16); f[3] = __uint_as_float(v.y & 0xffff0000u);
    f[4] = __uint_as_float(v.z << 16); f[5] = __uint_as_float(v.z & 0xffff0000u);
    f[6] = __uint_as_float(v.w << 16); f[7] = __uint_as_float(v.w & 0xffff0000u);
}

__global__ __launch_bounds__(NTHREADS, 4) void wavelet_synth_kernel(
    const float* __restrict__ coeffs, const int* __restrict__ rows,
    const int* __restrict__ cols, const float* __restrict__ ri_scale,
    const float* __restrict__ ri_shift, const float* __restrict__ freq_gain,
    const float* __restrict__ sw, float* __restrict__ out)
{
    __shared__ unsigned short zs[NCH * WIN];   // 48 KB, bf16 z tile
    __shared__ unsigned short wr[NCH * WROW];  // 16 KB, bf16 weights (forward j)

    const int tid = threadIdx.x;
    const int t0 = blockIdx.x * TT;
    const int b  = blockIdx.y;
    const int c  = blockIdx.z;
    const int rc = rows[c];
    const int cc = cols[c];

    // ---- stage z window: zs[i][x] = z[b, c, i, t0-64+x], affine fused, bf16 ----
    for (int idx = tid; idx < NCH * WIN; idx += NTHREADS) {
        int i  = idx / WIN;
        int x  = idx - i * WIN;
        int f  = i & (F_ - 1);
        int ri = i >> 5;
        int tau = t0 - 64 + x;
        float v = 0.f;
        if (tau >= 0 && tau < T_) {
            long off = ((((long)b * 2 + ri) * F_ + f) * 7 + rc) * 5 + cc;
            float raw = coeffs[off * T_ + tau];
            float inv = __builtin_amdgcn_rcpf(ri_scale[f] + 1e-12f);
            v = (raw * inv - ri_shift[f]) * freq_gain[f];
        }
        zs[idx] = f2bf(v);
    }
    // ---- stage weights j in [0,128) ----
    for (int idx = tid; idx < NCH * WROW; idx += NTHREADS) {
        int i = idx >> 7;
        int j = idx & (WROW - 1);
        wr[idx] = f2bf(sw[((long)c * NCH + i) * K_ + j]);
    }
    __syncthreads();

    const int tx = tid & 31;   // 32 t-octets -> outputs t0 + tx*8 + dt
    const int ig = tid >> 5;   // 16 channel groups of 4

    float acc[8];
    #pragma unroll
    for (int dt = 0; dt < 8; ++dt) acc[dt] = 0.f;

    for (int ic = 0; ic < 4; ++ic) {
        const int i = ig * 4 + ic;
        const unsigned short* zrow = &zs[i * WIN + tx * 8];
        const unsigned short* wrow = &wr[i * WROW];
        const float wlast = sw[((long)c * NCH + i) * K_ + 128];  // j = 128 tap

        // window f[k] = z_rel[(120 - j0) + k]; slides down by 8 each step
        float f[16];
        cvt8(*(const uint4*)(zrow + 120), f);
        cvt8(*(const uint4*)(zrow + 128), f + 8);
        #pragma unroll
        for (int j0 = 0; j0 <= 120; j0 += 8) {
            float wv[8];
            cvt8(*(const uint4*)(wrow + j0), wv);
            #pragma unroll
            for (int jj = 0; jj < 8; ++jj) {
                #pragma unroll
                for (int dt = 0; dt < 8; ++dt)
                    acc[dt] += f[dt + 8 - jj] * wv[jj];   // tau = t + 64 - (j0+jj)
            }
            if (j0 < 120) {
                #pragma unroll
                for (int k = 15; k >= 8; --k) f[k] = f[k - 8];
                cvt8(*(const uint4*)(zrow + (112 - j0)), f);
            }
        }
        // epilogue tap j = 128: window now at base_rel 0 -> f[dt] = z[t - 64]
        #pragma unroll
        for (int dt = 0; dt < 8; ++dt) acc[dt] += f[dt] * wlast;
    }

    __syncthreads();
    float* red = (float*)zs;   // overlay: 16 groups x 256 outputs = 16 KB
    #pragma unroll
    for (int dt = 0; dt < 8; ++dt) red[ig * TT + tx * 8 + dt] = acc[dt];
    __syncthreads();

    if (tid < TT) {
        float s = 0.f;
        #pragma unroll
        for (int g = 0; g < 16; ++g) s += red[g * TT + tid];
        out[((long)b * C_ + c) * T_ + t0 + tid] = s;
    }
}

extern "C" void kernel_launch(void* const* d_in, const int* in_sizes, int n_in,
                              void* d_out, int out_size, void* d_ws, size_t ws_size,
                              hipStream_t stream) {
    const float* coeffs    = (const float*)d_in[0];
    const int*   rows      = (const int*)d_in[1];
    const int*   cols      = (const int*)d_in[2];
    const float* ri_scale  = (const float*)d_in[3];
    const float* ri_shift  = (const float*)d_in[4];
    const float* freq_gain = (const float*)d_in[5];
    const float* sw        = (const float*)d_in[6];
    float* out = (float*)d_out;

    dim3 grid(T_ / TT, B_, C_);
    hipLaunchKernelGGL(wavelet_synth_kernel, grid, dim3(NTHREADS), 0, stream,
                       coeffs, rows, cols, ri_scale, ri_shift, freq_gain, sw, out);
}

// Round 2
// 685.498 us; speedup vs baseline: 5.3555x; 5.3555x over previous
//
#include <hip/hip_runtime.h>

typedef __attribute__((ext_vector_type(8))) short short8;
typedef __attribute__((ext_vector_type(4))) float f32x4;

#define B_ 16
#define C_ 32
#define T_ 2048
#define K_ 129
#define TT 128          // output t per block
#define NT 256          // tau window = TT + 128
#define ZP_STRIDE 68    // dwords per tau-pair row (64 i + 4 pad; 272 B, 16B-aligned)
#define W_STRIDE 72     // bf16 per W row (64 i + 8 pad; 144 B, 16B-aligned)
#define S_STRIDE 148    // f32 per Sj row (144 used + 4 pad)

__device__ __forceinline__ unsigned int bfround(float f) {
    unsigned int u = __float_as_uint(f);
    return u + 0x7fffu + ((u >> 16) & 1u);   // RNE to bf16 in high 16 bits
}

__global__ __launch_bounds__(256, 2) void wavelet_synth_mfma(
    const float* __restrict__ coeffs, const int* __restrict__ rows,
    const int* __restrict__ cols, const float* __restrict__ ri_scale,
    const float* __restrict__ ri_shift, const float* __restrict__ freq_gain,
    const float* __restrict__ sw, float* __restrict__ out)
{
    __shared__ unsigned int   Zp[128 * ZP_STRIDE];   // 34816 B: dword = (z[2r,i], z[2r+1,i]) bf16 pair
    __shared__ unsigned short Wl[144 * W_STRIDE];    // 20736 B: Wl[j][i] = bf16(sw[c,i,j]), j>=129 zero
    __shared__ float          Sj[16 * S_STRIDE];     //  9472 B: S tile for one j-phase

    const int tid = threadIdx.x;
    const int t0 = blockIdx.x * TT;
    const int b  = blockIdx.y;
    const int c  = blockIdx.z;
    const int rc = rows[c];
    const int cc = cols[c];

    // ---------------- stage Z (transposed, bf16 tau-pairs) ----------------
    {
        const int i3 = tid & 7;          // i sub-index (8 per wave for bank spread)
        const int to = tid >> 3;         // 0..31 -> tau base = to*8
        const int tbase = to * 8;
        #pragma unroll
        for (int it = 0; it < 8; ++it) {
            const int i  = i3 + 8 * it;
            const int f  = i & 31;
            const int ri = i >> 5;
            const float inv = __builtin_amdgcn_rcpf(ri_scale[f] + 1e-12f);
            const float sh  = ri_shift[f];
            const float g   = freq_gain[f];
            const long row = ((long)(b * 2 + ri) * 32 + f) * 35 + rc * 5 + cc;
            const float* src = coeffs + row * T_;
            const int tg = t0 - 64 + tbase;
            float v[8];
            if (tg >= 0 && tg + 8 <= T_) {
                float4 A  = *(const float4*)(src + tg);
                float4 Bv = *(const float4*)(src + tg + 4);
                v[0] = A.x;  v[1] = A.y;  v[2] = A.z;  v[3] = A.w;
                v[4] = Bv.x; v[5] = Bv.y; v[6] = Bv.z; v[7] = Bv.w;
                #pragma unroll
                for (int k = 0; k < 8; ++k) v[k] = (v[k] * inv - sh) * g;
            } else {
                #pragma unroll
                for (int k = 0; k < 8; ++k) {
                    const int t = tg + k;
                    v[k] = (t >= 0 && t < T_) ? (src[t] * inv - sh) * g : 0.f;
                }
            }
            #pragma unroll
            for (int k = 0; k < 4; ++k) {
                const unsigned int p = (bfround(v[2 * k]) >> 16) |
                                       (bfround(v[2 * k + 1]) & 0xffff0000u);
                Zp[(to * 4 + k) * ZP_STRIDE + i] = p;
            }
        }
    }
    // ---------------- stage W (transposed, bf16, zero-padded j) ----------------
    {
        const int iw = tid & 63;
        const int jq = tid >> 6;
        for (int j = jq; j < 144; j += 4) {
            const float wv = (j < K_) ? sw[((long)c * 64 + iw) * K_ + j] : 0.f;
            Wl[j * W_STRIDE + iw] = (unsigned short)(bfround(wv) >> 16);
        }
    }
    __syncthreads();

    // ---------------- 9 j-phases: MFMA S-tiles + diagonal reduce ----------------
    const int lane  = tid & 63;
    const int wv_id = tid >> 6;          // wave 0..3
    const int col   = lane & 15;
    const int quad  = lane >> 4;
    const unsigned int sel = (col & 1) ? 0x07060302u : 0x05040100u;  // parity extract
    float out_acc = 0.f;

    for (int jt = 0; jt < 9; ++jt) {
        const int lo = (jt < 8) ? (7 - jt) : 0;   // first tau-tile on the diagonal band
        const int nt = (jt < 8) ? 9 : 8;          // number of tau-tiles this phase

        // A-fragments: Wl[j = jt*16+col][i = 32h + quad*8 + e]
        const unsigned short* wrow = &Wl[(jt * 16 + col) * W_STRIDE + quad * 8];
        const short8 a0 = *(const short8*)(wrow);
        const short8 a1 = *(const short8*)(wrow + 32);

        for (int idx = wv_id; idx < nt; idx += 4) {
            const int tt = lo + idx;
            const int r  = tt * 8 + (col >> 1);   // tau-pair row for tau = tt*16+col
            const unsigned int* zrow = &Zp[r * ZP_STRIDE + quad * 8];
            const uint4 d01 = *(const uint4*)(zrow);        // i: q*8+0..3
            const uint4 d23 = *(const uint4*)(zrow + 4);    // i: q*8+4..7
            const uint4 d45 = *(const uint4*)(zrow + 32);   // i: 32+q*8+0..3
            const uint4 d67 = *(const uint4*)(zrow + 36);   // i: 32+q*8+4..7

            uint4 bu0, bu1;
            bu0.x = __builtin_amdgcn_perm(d01.y, d01.x, sel);
            bu0.y = __builtin_amdgcn_perm(d01.w, d01.z, sel);
            bu0.z = __builtin_amdgcn_perm(d23.y, d23.x, sel);
            bu0.w = __builtin_amdgcn_perm(d23.w, d23.z, sel);
            bu1.x = __builtin_amdgcn_perm(d45.y, d45.x, sel);
            bu1.y = __builtin_amdgcn_perm(d45.w, d45.z, sel);
            bu1.z = __builtin_amdgcn_perm(d67.y, d67.x, sel);
            bu1.w = __builtin_amdgcn_perm(d67.w, d67.z, sel);
            const short8 b0 = __builtin_bit_cast(short8, bu0);
            const short8 b1 = __builtin_bit_cast(short8, bu1);

            f32x4 acc = {0.f, 0.f, 0.f, 0.f};
            acc = __builtin_amdgcn_mfma_f32_16x16x32_bf16(a0, b0, acc, 0, 0, 0);
            acc = __builtin_amdgcn_mfma_f32_16x16x32_bf16(a1, b1, acc, 0, 0, 0);

            // D[row = quad*4 + rr][col] -> Sj[jl][taurel = idx*16 + col]
            #pragma unroll
            for (int rr = 0; rr < 4; ++rr)
                Sj[(quad * 4 + rr) * S_STRIDE + idx * 16 + col] = acc[rr];
        }
        __syncthreads();

        if (tid < TT) {
            float s = 0.f;
            if (jt < 8) {
                #pragma unroll
                for (int jl = 0; jl < 16; ++jl)
                    s += Sj[jl * S_STRIDE + tid + 16 - jl];   // taurel = dt + 16 - jl
            } else {
                #pragma unroll
                for (int jl = 0; jl < 16; ++jl) {
                    const int tr = tid - jl;                   // j = 128 + jl; jl>0 rows are zero
                    s += Sj[jl * S_STRIDE + (tr > 0 ? tr : 0)];
                }
            }
            out_acc += s;
        }
        __syncthreads();
    }

    if (tid < TT)
        out[((long)b * C_ + c) * T_ + t0 + tid] = out_acc;
}

extern "C" void kernel_launch(void* const* d_in, const int* in_sizes, int n_in,
                              void* d_out, int out_size, void* d_ws, size_t ws_size,
                              hipStream_t stream) {
    const float* coeffs    = (const float*)d_in[0];
    const int*   rows      = (const int*)d_in[1];
    const int*   cols      = (const int*)d_in[2];
    const float* ri_scale  = (const float*)d_in[3];
    const float* ri_shift  = (const float*)d_in[4];
    const float* freq_gain = (const float*)d_in[5];
    const float* sw        = (const float*)d_in[6];
    float* out = (float*)d_out;

    dim3 grid(T_ / TT, B_, C_);   // 16 x 16 x 32 = 8192 blocks
    hipLaunchKernelGGL(wavelet_synth_mfma, grid, dim3(256), 0, stream,
                       coeffs, rows, cols, ri_scale, ri_shift, freq_gain, sw, out);
}

// Round 3
// 545.102 us; speedup vs baseline: 6.7348x; 1.2576x over previous
//
#include <hip/hip_runtime.h>

typedef __attribute__((ext_vector_type(8))) short short8;
typedef __attribute__((ext_vector_type(4))) float f32x4;

#define B_ 16
#define C_ 32
#define T_ 2048
#define K_ 129
#define TT 128                 // output t per block
// Z LDS: row r (taurel 0..255) at bf16 offset r*72 + (r>>3)*8 (skew for banks)
#define ZROW(r) ((r) * 72 + (((r) >> 3) << 3))
#define ZSIZE (256 * 72 + 32 * 8)   // 18688 bf16 = 37376 B
#define SSLOT 272              // 16 rows x 17 f32
#define SWAVE 544              // 2 slots per wave

__device__ __forceinline__ unsigned int bfround(float f) {
    unsigned int u = __float_as_uint(f);
    return u + 0x7fffu + ((u >> 16) & 1u);   // RNE bf16 in high 16 bits
}

__global__ __launch_bounds__(256, 3) void wavelet_synth_v3(
    const float* __restrict__ coeffs, const int* __restrict__ rows,
    const int* __restrict__ cols, const float* __restrict__ ri_scale,
    const float* __restrict__ ri_shift, const float* __restrict__ freq_gain,
    const float* __restrict__ sw, float* __restrict__ out)
{
    __shared__ __align__(16) unsigned short Zl[ZSIZE];   // 37376 B
    __shared__ __align__(16) float Sw[4 * SWAVE];        //  8704 B

    const int tid = threadIdx.x;
    const int t0 = blockIdx.x * TT;
    const int b  = blockIdx.y;
    const int c  = blockIdx.z;
    const int rc = rows[c];
    const int cc = cols[c];

    // ---------------- stage Z: Zl[taurel][i] = bf16(affine(coeffs)) ----------------
    {
        const int i3 = tid & 7;
        const int to = tid >> 3;               // 0..31 -> taurel octet to*8
        const int tg0 = t0 - 64 + to * 8;
        const bool interior = (blockIdx.x >= 1) && (blockIdx.x <= 14);
        unsigned short* zr = &Zl[ZROW(to * 8)];   // rows 8to+k: base + 72*k (same skew)
        #pragma unroll
        for (int it = 0; it < 8; ++it) {
            const int i  = i3 + 8 * it;
            const int f  = i & 31;
            const int ri = i >> 5;
            const float inv = __builtin_amdgcn_rcpf(ri_scale[f] + 1e-12f);
            const float Aa  = inv * freq_gain[f];
            const float Bb  = -ri_shift[f] * freq_gain[f];
            const long  row = ((long)(b * 2 + ri) * 32 + f) * 35 + rc * 5 + cc;
            const float* src = coeffs + row * T_;
            float v[8];
            if (interior) {
                float4 x = *(const float4*)(src + tg0);
                float4 y = *(const float4*)(src + tg0 + 4);
                v[0] = x.x; v[1] = x.y; v[2] = x.z; v[3] = x.w;
                v[4] = y.x; v[5] = y.y; v[6] = y.z; v[7] = y.w;
                #pragma unroll
                for (int k = 0; k < 8; ++k) v[k] = v[k] * Aa + Bb;
            } else {
                #pragma unroll
                for (int k = 0; k < 8; ++k) {
                    const int t = tg0 + k;
                    v[k] = (t >= 0 && t < T_) ? src[t] * Aa + Bb : 0.f;
                }
            }
            #pragma unroll
            for (int k = 0; k < 8; ++k)
                zr[k * 72 + i] = (unsigned short)(bfround(v[k]) >> 16);
        }
    }
    __syncthreads();

    // ---------------- per-wave independent j-phases ----------------
    const int lane = tid & 63;
    const int wv   = tid >> 6;     // wave 0..3
    const int col  = lane & 15;
    const int q    = lane >> 4;
    float* mySw = &Sw[wv * SWAVE];

    float out_acc[8];
    #pragma unroll
    for (int a = 0; a < 8; ++a) out_acc[a] = 0.f;

    // compute S tile tt (taurel [16tt,16tt+16)) into my slot (tt&1)
    auto tile = [&](int tt, short8 a0, short8 a1) {
        const unsigned short* zp = &Zl[ZROW(16 * tt + col) + q * 8];
        const short8 b0 = *(const short8*)zp;
        const short8 b1 = *(const short8*)(zp + 32);
        f32x4 acc = {0.f, 0.f, 0.f, 0.f};
        acc = __builtin_amdgcn_mfma_f32_16x16x32_bf16(a0, b0, acc, 0, 0, 0);
        acc = __builtin_amdgcn_mfma_f32_16x16x32_bf16(a1, b1, acc, 0, 0, 0);
        float* s = &mySw[(tt & 1) * SSLOT];
        #pragma unroll
        for (int rr = 0; rr < 4; ++rr)
            s[(q * 4 + rr) * 17 + col] = acc[rr];   // row = jl, col = taurel local
    };

    for (int p = 0; p < 3; ++p) {
        const int jt = wv + 4 * p;     // wave 0: 0,4,8; wave 1: 1,5; wave 2: 2,6; wave 3: 3,7
        if (jt > 8) break;

        // A-fragments from global sw (L2-hot): A[m=col -> j][k -> i]
        const int j = 16 * jt + col;
        const bool jok = (j < K_);
        const float* wbase = sw + (long)c * 64 * K_ + j;
        short8 a0, a1;
        #pragma unroll
        for (int e = 0; e < 8; ++e) {
            const int i0 = q * 8 + e;
            const float w0 = jok ? wbase[(long)i0 * K_] : 0.f;
            const float w1 = jok ? wbase[(long)(i0 + 32) * K_] : 0.f;
            a0[e] = (short)(bfround(w0) >> 16);
            a1[e] = (short)(bfround(w1) >> 16);
        }

        if (jt < 8) {
            tile(7 - jt, a0, a1);                 // prime lower tile
        } else {
            float* s1 = &mySw[SSLOT];             // tile "-1" = zeros (j>128 rows are 0 anyway)
            for (int n = lane; n < SSLOT; n += 64) s1[n] = 0.f;
        }

        #pragma unroll
        for (int a = 0; a < 8; ++a) {
            const int tt = a + 8 - jt;
            tile(tt, a0, a1);
            // reduce chunk a: out[16a+r] += sum_jl S[jl][taurel = 16a+r+16-jl (local band)]
            const float* s1 = &mySw[(tt & 1) * SSLOT];
            const float* s0 = &mySw[((tt & 1) ^ 1) * SSLOT];
            float v = 0.f;
            #pragma unroll
            for (int u = 0; u < 4; ++u) {
                const int jl = q * 4 + u;
                const float* sp = (col >= jl) ? s1 : s0;
                v += sp[jl * 17 + ((col - jl) & 15)];
            }
            v += __shfl_xor(v, 16);
            v += __shfl_xor(v, 32);
            out_acc[a] += v;       // all lanes: value for r = lane&15, dt = 16a+r
        }
    }

    // ---------------- cross-wave combine (reuse Sw as partial buffer) ----------------
    if (lane < 16) {
        #pragma unroll
        for (int a = 0; a < 8; ++a)
            mySw[a * 16 + lane] = out_acc[a];
    }
    __syncthreads();

    if (tid < TT) {
        const float sres = Sw[tid] + Sw[SWAVE + tid] +
                           Sw[2 * SWAVE + tid] + Sw[3 * SWAVE + tid];
        out[((long)b * C_ + c) * T_ + t0 + tid] = sres;
    }
}

extern "C" void kernel_launch(void* const* d_in, const int* in_sizes, int n_in,
                              void* d_out, int out_size, void* d_ws, size_t ws_size,
                              hipStream_t stream) {
    const float* coeffs    = (const float*)d_in[0];
    const int*   rows      = (const int*)d_in[1];
    const int*   cols      = (const int*)d_in[2];
    const float* ri_scale  = (const float*)d_in[3];
    const float* ri_shift  = (const float*)d_in[4];
    const float* freq_gain = (const float*)d_in[5];
    const float* sw        = (const float*)d_in[6];
    float* out = (float*)d_out;

    dim3 grid(T_ / TT, B_, C_);   // 16 x 16 x 32 = 8192 blocks
    hipLaunchKernelGGL(wavelet_synth_v3, grid, dim3(256), 0, stream,
                       coeffs, rows, cols, ri_scale, ri_shift, freq_gain, sw, out);
}

// Round 4
// 456.346 us; speedup vs baseline: 8.0447x; 1.1945x over previous
//
#include <hip/hip_runtime.h>

typedef __attribute__((ext_vector_type(8))) short short8;
typedef __attribute__((ext_vector_type(4))) float f32x4;

#define C_ 32
#define T_ 2048
#define K_ 129
// z LDS tile: rows of 16 tau-l (bf16) padded to 24 els (48 B) -> conflict-free
#define ZROWS (12 * 8 * 16)          // vi(12) x il(8) x b(16)
#define ZS_USHORT (ZROWS * 24)       // 36864 ushort = 73728 B

__device__ __forceinline__ unsigned int bfround(float f) {
    unsigned int u = __float_as_uint(f);
    return u + 0x7fffu + ((u >> 16) & 1u);   // RNE bf16 in high 16 bits
}

// ---- k0: pack Toeplitz-W A-fragments into d_ws ----
// A_{c,d,iq,igl}[m, k=(i2,tl)] = bf16( sw[c, iq*8+igl*2+i2, 16d+64+m-tl] ), j-OOB = 0
__global__ __launch_bounds__(256) void wtoep_pack(
    const float* __restrict__ sw, unsigned short* __restrict__ wt)
{
    const int c = blockIdx.x, dd = blockIdx.y;     // 32 x 9
    const int t = threadIdx.x, l = t & 63, fw = t >> 6;
    const int m = l & 15, qb = (l >> 4) & 1, i2 = (l >> 5) & 1;
    const int d = dd - 4;
    for (int fr = fw; fr < 32; fr += 4) {          // fr = iq*4 + igl
        const int iq = fr >> 2, igl = fr & 3;
        const int i = iq * 8 + igl * 2 + i2;
        unsigned short v[8];
        #pragma unroll
        for (int e = 0; e < 8; ++e) {
            const int tl = 8 * qb + e;
            const int j = 16 * d + 64 + m - tl;
            const float wv = (j >= 0 && j <= 128) ? sw[(c * 64 + i) * K_ + j] : 0.f;
            v[e] = (unsigned short)(bfround(wv) >> 16);
        }
        *(short8*)(wt + (((c * 9 + dd) * 32 + fr) * 64 + l) * 8) = *(short8*)v;
    }
}

// ---- k2: batched-b MFMA conv ----
__global__ __launch_bounds__(256, 2) void wavelet_synth_v4(
    const float* __restrict__ coeffs, const int* __restrict__ rows,
    const int* __restrict__ cols, const float* __restrict__ ri_scale,
    const float* __restrict__ ri_shift, const float* __restrict__ freq_gain,
    const unsigned short* __restrict__ wt, float* __restrict__ out)
{
    __shared__ __align__(16) unsigned short zs[ZS_USHORT];   // 73728 B

    const int t  = threadIdx.x;
    const int g0 = blockIdx.x * 4;      // 4 g-tiles (64 outputs x16 = 256 t? no: 4*16 = 64 t) per block
    const int c  = blockIdx.y;
    const int rc = rows[c];
    const int cc = cols[c];

    const int lane = t & 63;
    const int w    = t >> 6;            // wave id = i-pair (igl)
    const int i2   = (lane >> 5) & 1;
    const int qb   = (lane >> 4) & 1;

    f32x4 acc0 = {0,0,0,0}, acc1 = {0,0,0,0}, acc2 = {0,0,0,0}, acc3 = {0,0,0,0};

    // staging chunk decomposition (per phase: 12 chunks of 8 tau each)
    const int s_r  = t & 1;
    const int s_b  = (t >> 1) & 15;
    const int s_il = (t >> 5) & 7;      // + 8*p carries vi

    for (int iq = 0; iq < 8; ++iq) {
        __syncthreads();   // previous phase's reads done before overwrite
        // ---- stage: zs[vi][il][b][tl] = bf16(affine(coeffs)), vi in [0,12) ----
        for (int p = 0; p < 12; ++p) {
            const int cn = p * 256 + t;
            const int vi = cn >> 8;                       // 0..11
            const int il = s_il + ((p & 1) ? 0 : 0);      // il low bit from t, high from p
            const int ilf = (cn >> 5) & 7;
            const int v_abs = g0 - 4 + vi;
            const int i  = iq * 8 + ilf;
            const int f  = i & 31;
            const int ri = i >> 5;
            float vv[8];
            if (v_abs >= 0 && v_abs < 128) {
                const float inv = __builtin_amdgcn_rcpf(ri_scale[f] + 1e-12f);
                const float Aa  = inv * freq_gain[f];
                const float Bb  = -ri_shift[f] * freq_gain[f];
                const long  row = ((long)(s_b * 2 + ri) * 32 + f) * 35 + rc * 5 + cc;
                const float* src = coeffs + row * T_ + v_abs * 16 + s_r * 8;
                const float4 x = *(const float4*)(src);
                const float4 y = *(const float4*)(src + 4);
                vv[0] = x.x * Aa + Bb; vv[1] = x.y * Aa + Bb;
                vv[2] = x.z * Aa + Bb; vv[3] = x.w * Aa + Bb;
                vv[4] = y.x * Aa + Bb; vv[5] = y.y * Aa + Bb;
                vv[6] = y.z * Aa + Bb; vv[7] = y.w * Aa + Bb;
            } else {
                #pragma unroll
                for (int e = 0; e < 8; ++e) vv[e] = 0.f;
            }
            unsigned short pk[8];
            #pragma unroll
            for (int e = 0; e < 8; ++e) pk[e] = (unsigned short)(bfround(vv[e]) >> 16);
            *(short8*)(zs + ((vi * 8 + ilf) * 16 + s_b) * 24 + s_r * 8) = *(short8*)pk;
        }
        __syncthreads();

        // ---- compute: 9 d-shifts x 4 g-tiles, acc in regs ----
        const unsigned short* wbase = wt + ((c * 9) * 32 + iq * 4 + w) * 512 + lane * 8;
        for (int d = 0; d < 9; ++d) {
            const short8 afrag = *(const short8*)(wbase + d * 32 * 512);
            const int vbase = 8 - d;    // vi = g + 8 - d
            const unsigned short* zb =
                zs + ((w * 2 + i2) * 16 + (lane & 15)) * 24 + qb * 8;
            const short8 b0 = *(const short8*)(zb + (vbase + 0) * (8 * 16 * 24));
            acc0 = __builtin_amdgcn_mfma_f32_16x16x32_bf16(afrag, b0, acc0, 0, 0, 0);
            const short8 b1 = *(const short8*)(zb + (vbase + 1) * (8 * 16 * 24));
            acc1 = __builtin_amdgcn_mfma_f32_16x16x32_bf16(afrag, b1, acc1, 0, 0, 0);
            const short8 b2 = *(const short8*)(zb + (vbase + 2) * (8 * 16 * 24));
            acc2 = __builtin_amdgcn_mfma_f32_16x16x32_bf16(afrag, b2, acc2, 0, 0, 0);
            const short8 b3 = *(const short8*)(zb + (vbase + 3) * (8 * 16 * 24));
            acc3 = __builtin_amdgcn_mfma_f32_16x16x32_bf16(afrag, b3, acc3, 0, 0, 0);
        }
    }

    // ---- cross-wave reduce + store ----
    __syncthreads();
    float* red = (float*)zs;    // 16 tiles x 64 lanes x 4 f32 = 16 KB
    *(f32x4*)(red + ((w * 4 + 0) * 64 + lane) * 4) = acc0;
    *(f32x4*)(red + ((w * 4 + 1) * 64 + lane) * 4) = acc1;
    *(f32x4*)(red + ((w * 4 + 2) * 64 + lane) * 4) = acc2;
    *(f32x4*)(red + ((w * 4 + 3) * 64 + lane) * 4) = acc3;
    __syncthreads();

    {
        const int s  = t & 3;
        const int b  = (t >> 2) & 15;
        const int g  = t >> 6;
        float4 o;
        float* po = (float*)&o;
        #pragma unroll
        for (int rr = 0; rr < 4; ++rr) {
            float sum = 0.f;
            #pragma unroll
            for (int ww = 0; ww < 4; ++ww)
                sum += red[((ww * 4 + g) * 64 + s * 16 + b) * 4 + rr];
            po[rr] = sum;
        }
        *(float4*)(out + ((long)b * C_ + c) * T_ + (g0 + g) * 16 + s * 4) = o;
    }
}

extern "C" void kernel_launch(void* const* d_in, const int* in_sizes, int n_in,
                              void* d_out, int out_size, void* d_ws, size_t ws_size,
                              hipStream_t stream) {
    const float* coeffs    = (const float*)d_in[0];
    const int*   rows      = (const int*)d_in[1];
    const int*   cols      = (const int*)d_in[2];
    const float* ri_scale  = (const float*)d_in[3];
    const float* ri_shift  = (const float*)d_in[4];
    const float* freq_gain = (const float*)d_in[5];
    const float* sw        = (const float*)d_in[6];
    float* out = (float*)d_out;
    unsigned short* wt = (unsigned short*)d_ws;   // needs 32*9*32*512*2 = 9,437,184 B

    hipLaunchKernelGGL(wtoep_pack, dim3(32, 9), dim3(256), 0, stream, sw, wt);
    hipLaunchKernelGGL(wavelet_synth_v4, dim3(32, 32), dim3(256), 0, stream,
                       coeffs, rows, cols, ri_scale, ri_shift, freq_gain, wt, out);
}